// Round 14
// baseline (350.123 us; speedup 1.0000x reference)
//
#include <hip/hip_runtime.h>
#include <stdint.h>

typedef uint32_t u32;
typedef uint16_t u16;

static constexpr int M_DIM = 8192;
static constexpr int N_DIM = 1024;
static constexpr int K_DIM = 4096;

// Wt frag-major: [nb16(64)][kt32(128)] frags of 1 KiB; frag lane l = kq*16+row16 holds 16 B.
static constexpr size_t FRAG_U16 = 512;
static constexpr size_t WT_BYTES = 64ull * 128 * FRAG_U16 * 2;  // 8 MiB
static constexpr size_t WS_NEEDED = WT_BYTES;

typedef __attribute__((ext_vector_type(8))) _Float16 half8;  // MFMA A/B frag (4 VGPRs)
typedef __attribute__((ext_vector_type(4))) float f32x4;     // MFMA C/D frag

__device__ __forceinline__ u32 pack2(float a, float b) {
  union { _Float16 h[2]; u32 u; } p;
  p.h[0] = (_Float16)a;   // v_cvt_f16_f32, RNE
  p.h[1] = (_Float16)b;
  return p.u;
}

// GELU via Abramowitz-Stegun 7.1.26 erf (|err| <= 1.5e-7) + dropout keep-mask * 1/(1-0.1).
__device__ __forceinline__ float gelu_drop(float x, u32 keep) {
  float ax = fabsf(x);
  float z  = ax * 0.70710678f;
  float t  = __builtin_amdgcn_rcpf(fmaf(0.3275911f, z, 1.0f));
  float poly = fmaf(fmaf(fmaf(fmaf(1.061405429f, t, -1.453152027f),
                              t, 1.421413741f),
                         t, -0.284496736f),
                    t, 0.254829592f) * t;
  float e   = exp2f(z * z * -1.44269504f);    // exp(-z^2)
  float erf = fmaf(-poly, e, 1.0f);           // erf(|x|/sqrt(2)) in [0,1)
  float g   = 0.5f * x * (1.0f + copysignf(erf, x));
  return keep ? g * 1.1111112f : 0.0f;
}

// ---------------- W prepack (verified R3-R13): 17 MB f32 -> 8 MB fp16 frag-major ----------------
static constexpr int W_PAIRS = 64 * 64;          // nb(64) x kp(64)
static constexpr int WPACK_BLOCKS = W_PAIRS / 4; // 1024

__global__ __launch_bounds__(256)
void wpack_kernel(const float* __restrict__ W, u16* __restrict__ Wt) {
  const int l     = threadIdx.x & 63;
  const int pj    = blockIdx.x * 4 + (threadIdx.x >> 6);
  const int row16 = l & 15;
  const int kof   = (l >> 4) << 4;          // 0,16,32,48 within the 64-k pair
  const int fsub  = kof >> 5;               // 0 or 1
  const int q0    = (kof & 31) >> 3;        // 0 or 2

  const int nb = pj >> 6, kp = pj & 63;
  const float* wp = W + (size_t)(nb * 16 + row16) * K_DIM + kp * 64 + kof;
  float4 w0 = *(const float4*)(wp + 0);
  float4 w1 = *(const float4*)(wp + 4);
  float4 w2 = *(const float4*)(wp + 8);
  float4 w3 = *(const float4*)(wp + 12);
  const int f = kp * 2 + fsub;
  u16* dst = Wt + (size_t)(nb * 128 + f) * FRAG_U16 + (size_t)(row16 + 16 * q0) * 8;
  *(uint4*)(dst)       = make_uint4(pack2(w0.x, w0.y), pack2(w0.z, w0.w),
                                    pack2(w1.x, w1.y), pack2(w1.z, w1.w));
  *(uint4*)(dst + 128) = make_uint4(pack2(w2.x, w2.y), pack2(w2.z, w2.w),
                                    pack2(w3.x, w3.y), pack2(w3.z, w3.w));
}

// ---------------- fused GELU+dropout+GEMM: BM=64 x BN=512, 16 waves, 4-deep B ring ----------------
// R13's verified machinery (mapping, no-dup B, A-swizzle, 16-wave TLP, epilogue) + 2 changes:
//  (1) B prefetch ring deepened 2 -> 4 (kt+4..kt+7 in flight; ring slot = ktl, all static).
//  (2) writeA / loadX redistributed between steps (after step0 / step1) so the gelu-VALU
//      burst and X-issue hide under MFMA/LDS waits instead of heading the chunk.
__global__ __launch_bounds__(1024, 4)
void fused_gemm_kernel(const float* __restrict__ X, const int* __restrict__ Mask,
                       const u16* __restrict__ Wt, const float* __restrict__ Bias,
                       float* __restrict__ Out) {
  __shared__ __attribute__((aligned(16))) u16 Abuf[2][8192];  // 2 x 16 KiB

  const int tid  = threadIdx.x;
  const int lane = tid & 63;
  const int wv   = tid >> 6;          // 0..15 : column sixteenth (32 cols)

  // ---- mapping (verified R11-R13): same-stripe pair co-XCD ----
  const int bid = blockIdx.x;
  const int xcd = bid & 7;
  const int j   = bid >> 3;                        // 0..31
  const int it  = xcd * 16 + (j >> 1);             // row tile 0..127
  const int jh  = j & 1;                           // column half 0/1
  const int m0  = it * 64;
  const int n0  = jh * 512;

  // ---- X/mask register staging: 8 elems/thread per 128-k chunk (verified R13) ----
  const int xrow = tid >> 4;          // 0..63
  const int xe8  = tid & 15;          // k-octet 0..15
  const float* Xp = X    + (size_t)(m0 + xrow) * K_DIM + xe8 * 8;
  const int*   Mp = Mask + (size_t)(m0 + xrow) * K_DIM + xe8 * 8;
  float4 xs0, xs1;
  uint4  ms0, ms1;
  auto loadX = [&](int c) {
    const float* xp = Xp + c * 128;
    const int*   mp = Mp + c * 128;
    xs0 = *(const float4*)(xp + 0);
    xs1 = *(const float4*)(xp + 4);
    ms0 = *(const uint4*)(mp + 0);
    ms1 = *(const uint4*)(mp + 4);
  };
  // A chunk layout (verified R12/R13): frag = kt*4+rf (1 KiB), slot (kq,r16) at kq*256+r16*16;
  // phys = logical ^ ((kt<<4)|((kq>>1)<<6)). Thread: kt=xe8>>2, kq=xe8&3 (one 16-B slot).
  const u32 kt_w = (u32)(xe8 >> 2), kq_w = (u32)(xe8 & 3);
  const u32 aBase = (((kt_w * 4 + (u32)(xrow >> 4)) * 1024) + kq_w * 256 +
                     (u32)(xrow & 15) * 16) ^
                    ((kt_w << 4) | ((kq_w >> 1) << 6));
  auto writeA = [&](int buf) {
    u32 o0 = pack2(gelu_drop(xs0.x, ms0.x), gelu_drop(xs0.y, ms0.y));
    u32 o1 = pack2(gelu_drop(xs0.z, ms0.z), gelu_drop(xs0.w, ms0.w));
    u32 o2 = pack2(gelu_drop(xs1.x, ms1.x), gelu_drop(xs1.y, ms1.y));
    u32 o3 = pack2(gelu_drop(xs1.z, ms1.z), gelu_drop(xs1.w, ms1.w));
    *(uint4*)((char*)Abuf[buf] + aBase) = make_uint4(o0, o1, o2, o3);
  };

  // ---- B: direct global->reg, 2 frags/wave/kt (wave cols = n0 + wv*32), 4-deep ring ----
  const char* WtB = (const char*)Wt;
  const size_t bBase = (size_t)(jh * 32 + wv * 2) * 131072 + (size_t)lane * 16;
  half8 bs0[2], bs1[2], bs2[2], bs3[2];
  auto loadB = [&](int kt, half8 (&bs)[2]) {
#pragma unroll
    for (int jj = 0; jj < 2; ++jj)
      bs[jj] = *(const half8*)(WtB + bBase + (size_t)jj * 131072 + (size_t)kt * 1024);
  };

  f32x4 acc[4][2];
#pragma unroll
  for (int i = 0; i < 4; ++i)
#pragma unroll
    for (int jj = 0; jj < 2; ++jj)
      acc[i][jj] = (f32x4){0.f, 0.f, 0.f, 0.f};

  // one kt step: 4 A ds_reads (swizzled, verified R12/R13) + 8 MFMA
  auto step = [&](int ab, int ktl, half8 (&bs)[2]) {
    const u32 rSwz = ((u32)ktl << 4) | (((u32)(lane >> 5) & 1u) << 6);
    half8 ar[4];
#pragma unroll
    for (int rf = 0; rf < 4; ++rf)
      ar[rf] = *(const half8*)((const char*)Abuf[ab] +
                               ((((u32)(ktl * 4 + rf) * 1024) + (u32)lane * 16) ^ rSwz));
    __builtin_amdgcn_s_setprio(1);
#pragma unroll
    for (int rf = 0; rf < 4; ++rf)
#pragma unroll
      for (int jj = 0; jj < 2; ++jj)
        acc[rf][jj] = __builtin_amdgcn_mfma_f32_16x16x32_f16(ar[rf], bs[jj], acc[rf][jj], 0, 0, 0);
    __builtin_amdgcn_s_setprio(0);
  };

  // ---- prologue: chunk 0 in LDS, X(1) in regs, B kts 0-3 in flight ----
  loadX(0);
  writeA(0);          // compiler waits on X loads
  loadX(1);           // for chunk 1 (gelu'd inside c=0)
  loadB(0, bs0);
  loadB(1, bs1);
  loadB(2, bs2);
  loadB(3, bs3);
  asm volatile("s_waitcnt lgkmcnt(0)" ::: "memory");
  __builtin_amdgcn_s_barrier();

#pragma unroll 1
  for (int c = 0; c < 32; ++c) {
    const int ab = c & 1;
    const int kt0 = c * 4;
    // step 0; then refill ring slot 0 and do the gelu burst for chunk c+1
    step(ab, 0, bs0);
    if (kt0 + 4 < 128) loadB(kt0 + 4, bs0);
    if (c + 1 < 32) writeA(ab ^ 1);
    // step 1; refill slot 1; issue X for chunk c+2
    step(ab, 1, bs1);
    if (kt0 + 5 < 128) loadB(kt0 + 5, bs1);
    if (c + 2 < 32) loadX(c + 2);
    // steps 2,3; refill slots 2,3
    step(ab, 2, bs2);
    if (kt0 + 6 < 128) loadB(kt0 + 6, bs2);
    step(ab, 3, bs3);
    if (kt0 + 7 < 128) loadB(kt0 + 7, bs3);
    // barrier: next chunk reads buf ab^1 (written above by all threads)
    if (c + 1 < 32) {
      asm volatile("s_waitcnt lgkmcnt(0)" ::: "memory");
      __builtin_amdgcn_s_barrier();
    }
  }

  // ---- epilogue: C/D layout col = lane&15, row = (lane>>4)*4 + reg [verified R3-R13] ----
  const int fr = lane & 15;
  const int rq = (lane >> 4) << 2;
#pragma unroll
  for (int rf = 0; rf < 4; ++rf) {
    const int row0 = m0 + rf * 16 + rq;
#pragma unroll
    for (int jj = 0; jj < 2; ++jj) {
      const int col = n0 + wv * 32 + jj * 16 + fr;
      const float b = Bias[col];
#pragma unroll
      for (int r = 0; r < 4; ++r)
        Out[(size_t)(row0 + r) * N_DIM + col] = acc[rf][jj][r] + b;
    }
  }
}

// ---------------- fallback: verified R3 fused kernel (only if ws too small) ----------------
static constexpr int A_STRIDE = 40;

__global__ __launch_bounds__(256, 2)
void fused_fallback_kernel(const float* __restrict__ X, const float* __restrict__ W,
                           const float* __restrict__ Bias, const int* __restrict__ Mask,
                           float* __restrict__ Out) {
  __shared__ __attribute__((aligned(16))) _Float16 As[128 * A_STRIDE];
  __shared__ __attribute__((aligned(16))) _Float16 Bs[128 * 32];

  const int tid  = threadIdx.x;
  const int lane = tid & 63;
  const int wv   = tid >> 6;
  const int wr   = wv >> 1;
  const int wc   = wv & 1;
  const int bm = blockIdx.x & 63;
  const int bn = blockIdx.x >> 6;
  const int m0 = bm * 128;
  const int n0 = bn * 128;

  const int a_m = tid >> 1;
  const int a_k = (tid & 1) << 4;
  const float* xptr = X    + (size_t)(m0 + a_m) * K_DIM + a_k;
  const int*   mptr = Mask + (size_t)(m0 + a_m) * K_DIM + a_k;
  _Float16* a_lds = &As[a_m * A_STRIDE + a_k];

  const int i0 = tid, i1 = tid + 256;
  const float* wp0 = W + (size_t)(n0 + (i0 >> 2)) * K_DIM + ((i0 & 3) << 3);
  const float* wp1 = W + (size_t)(n0 + (i1 >> 2)) * K_DIM + ((i1 & 3) << 3);
  _Float16* bl0 = &Bs[i0 * 8];
  _Float16* bl1 = &Bs[i1 * 8];

  f32x4 acc[4][4];
#pragma unroll
  for (int i = 0; i < 4; ++i)
#pragma unroll
    for (int j = 0; j < 4; ++j)
      acc[i][j] = (f32x4){0.f, 0.f, 0.f, 0.f};

  float4 xf0 = *(const float4*)(xptr +  0);
  float4 xf1 = *(const float4*)(xptr +  4);
  float4 xf2 = *(const float4*)(xptr +  8);
  float4 xf3 = *(const float4*)(xptr + 12);
  uint4  mr0 = *(const uint4*)(mptr +  0);
  uint4  mr1 = *(const uint4*)(mptr +  4);
  uint4  mr2 = *(const uint4*)(mptr +  8);
  uint4  mr3 = *(const uint4*)(mptr + 12);
  float4 wf0 = *(const float4*)(wp0 + 0);
  float4 wf1 = *(const float4*)(wp0 + 4);
  float4 wf2 = *(const float4*)(wp1 + 0);
  float4 wf3 = *(const float4*)(wp1 + 4);

#pragma unroll 1
  for (int kt = 0; kt < 128; ++kt) {
    {
      float xs[16] = {xf0.x, xf0.y, xf0.z, xf0.w, xf1.x, xf1.y, xf1.z, xf1.w,
                      xf2.x, xf2.y, xf2.z, xf2.w, xf3.x, xf3.y, xf3.z, xf3.w};
      u32 mk[16]   = {mr0.x, mr0.y, mr0.z, mr0.w, mr1.x, mr1.y, mr1.z, mr1.w,
                      mr2.x, mr2.y, mr2.z, mr2.w, mr3.x, mr3.y, mr3.z, mr3.w};
      u32 ow[8];
#pragma unroll
      for (int e = 0; e < 8; ++e)
        ow[e] = pack2(gelu_drop(xs[2 * e], mk[2 * e]), gelu_drop(xs[2 * e + 1], mk[2 * e + 1]));
      ((uint4*)a_lds)[0] = make_uint4(ow[0], ow[1], ow[2], ow[3]);
      ((uint4*)a_lds)[1] = make_uint4(ow[4], ow[5], ow[6], ow[7]);
    }
    {
      *(uint4*)bl0 = make_uint4(pack2(wf0.x, wf0.y), pack2(wf0.z, wf0.w),
                                pack2(wf1.x, wf1.y), pack2(wf1.z, wf1.w));
      *(uint4*)bl1 = make_uint4(pack2(wf2.x, wf2.y), pack2(wf2.z, wf2.w),
                                pack2(wf3.x, wf3.y), pack2(wf3.z, wf3.w));
    }
    __syncthreads();

    if (kt + 1 < 128) {
      xptr += 32; mptr += 32; wp0 += 32; wp1 += 32;
      xf0 = *(const float4*)(xptr +  0);
      xf1 = *(const float4*)(xptr +  4);
      xf2 = *(const float4*)(xptr +  8);
      xf3 = *(const float4*)(xptr + 12);
      mr0 = *(const uint4*)(mptr +  0);
      mr1 = *(const uint4*)(mptr +  4);
      mr2 = *(const uint4*)(mptr +  8);
      mr3 = *(const uint4*)(mptr + 12);
      wf0 = *(const float4*)(wp0 + 0);
      wf1 = *(const float4*)(wp0 + 4);
      wf2 = *(const float4*)(wp1 + 0);
      wf3 = *(const float4*)(wp1 + 4);
    }

    {
      const int fr2 = lane & 15;
      const int fk2 = (lane >> 4) << 3;
      half8 ar[4], br[4];
#pragma unroll
      for (int i = 0; i < 4; ++i)
        ar[i] = *(const half8*)&As[(wr * 64 + i * 16 + fr2) * A_STRIDE + fk2];
#pragma unroll
      for (int j = 0; j < 4; ++j)
        br[j] = *(const half8*)&Bs[(wc * 64 + j * 16 + fr2) * 32 + fk2];
#pragma unroll
      for (int i = 0; i < 4; ++i)
#pragma unroll
        for (int j = 0; j < 4; ++j)
          acc[i][j] = __builtin_amdgcn_mfma_f32_16x16x32_f16(ar[i], br[j], acc[i][j], 0, 0, 0);
    }
    __syncthreads();
  }

  const int fr = lane & 15;
  const int rq = (lane >> 4) << 2;
  float bv[4];
#pragma unroll
  for (int j = 0; j < 4; ++j)
    bv[j] = Bias[n0 + wc * 64 + j * 16 + fr];
#pragma unroll
  for (int i = 0; i < 4; ++i) {
    const int row0 = m0 + wr * 64 + i * 16 + rq;
#pragma unroll
    for (int j = 0; j < 4; ++j) {
      const int col = n0 + wc * 64 + j * 16 + fr;
#pragma unroll
      for (int r = 0; r < 4; ++r)
        Out[(size_t)(row0 + r) * N_DIM + col] = acc[i][j][r] + bv[j];
    }
  }
}

extern "C" void kernel_launch(void* const* d_in, const int* in_sizes, int n_in,
                              void* d_out, int out_size, void* d_ws, size_t ws_size,
                              hipStream_t stream) {
  const float* X    = (const float*)d_in[0];   // x (8192x4096), fp16 canonicalized to f32
  const float* W    = (const float*)d_in[1];   // weight (1024x4096) f32, K-contiguous
  const float* Bias = (const float*)d_in[2];   // bias (1024) f32
  const int*   Mk   = (const int*)d_in[3];     // keep-mask int32 0/1
  float* Out = (float*)d_out;                  // y (8192x1024) f32

  if (ws_size >= WS_NEEDED) {
    u16* Wt = (u16*)d_ws;
    wpack_kernel<<<WPACK_BLOCKS, 256, 0, stream>>>(W, Wt);
    fused_gemm_kernel<<<256, 1024, 0, stream>>>(X, Mk, Wt, Bias, Out);
  } else {
    fused_fallback_kernel<<<64 * 8, 256, 0, stream>>>(X, W, Bias, Mk, Out);
  }
}

// Round 15
// 346.850 us; speedup vs baseline: 1.0094x; 1.0094x over previous
//
#include <hip/hip_runtime.h>
#include <stdint.h>

typedef uint32_t u32;
typedef uint16_t u16;

static constexpr int M_DIM = 8192;
static constexpr int N_DIM = 1024;
static constexpr int K_DIM = 4096;

// Wt frag-major: [nb16(64)][kt32(128)] frags of 1 KiB; frag lane l = kq*16+row16 holds 16 B.
static constexpr size_t FRAG_U16 = 512;
static constexpr size_t WT_BYTES = 64ull * 128 * FRAG_U16 * 2;  // 8 MiB
static constexpr size_t WS_NEEDED = WT_BYTES;

typedef __attribute__((ext_vector_type(8))) _Float16 half8;  // MFMA A/B frag (4 VGPRs)
typedef __attribute__((ext_vector_type(4))) float f32x4;     // MFMA C/D frag

__device__ __forceinline__ u32 pack2(float a, float b) {
  union { _Float16 h[2]; u32 u; } p;
  p.h[0] = (_Float16)a;   // v_cvt_f16_f32, RNE
  p.h[1] = (_Float16)b;
  return p.u;
}

// GELU via Abramowitz-Stegun 7.1.26 erf (|err| <= 1.5e-7) + dropout keep-mask * 1/(1-0.1).
__device__ __forceinline__ float gelu_drop(float x, u32 keep) {
  float ax = fabsf(x);
  float z  = ax * 0.70710678f;
  float t  = __builtin_amdgcn_rcpf(fmaf(0.3275911f, z, 1.0f));
  float poly = fmaf(fmaf(fmaf(fmaf(1.061405429f, t, -1.453152027f),
                              t, 1.421413741f),
                         t, -0.284496736f),
                    t, 0.254829592f) * t;
  float e   = exp2f(z * z * -1.44269504f);    // exp(-z^2)
  float erf = fmaf(-poly, e, 1.0f);           // erf(|x|/sqrt(2)) in [0,1)
  float g   = 0.5f * x * (1.0f + copysignf(erf, x));
  return keep ? g * 1.1111112f : 0.0f;
}

// ---------------- W prepack (verified R3-R14): 17 MB f32 -> 8 MB fp16 frag-major ----------------
static constexpr int W_PAIRS = 64 * 64;          // nb(64) x kp(64)
static constexpr int WPACK_BLOCKS = W_PAIRS / 4; // 1024

__global__ __launch_bounds__(256)
void wpack_kernel(const float* __restrict__ W, u16* __restrict__ Wt) {
  const int l     = threadIdx.x & 63;
  const int pj    = blockIdx.x * 4 + (threadIdx.x >> 6);
  const int row16 = l & 15;
  const int kof   = (l >> 4) << 4;          // 0,16,32,48 within the 64-k pair
  const int fsub  = kof >> 5;               // 0 or 1
  const int q0    = (kof & 31) >> 3;        // 0 or 2

  const int nb = pj >> 6, kp = pj & 63;
  const float* wp = W + (size_t)(nb * 16 + row16) * K_DIM + kp * 64 + kof;
  float4 w0 = *(const float4*)(wp + 0);
  float4 w1 = *(const float4*)(wp + 4);
  float4 w2 = *(const float4*)(wp + 8);
  float4 w3 = *(const float4*)(wp + 12);
  const int f = kp * 2 + fsub;
  u16* dst = Wt + (size_t)(nb * 128 + f) * FRAG_U16 + (size_t)(row16 + 16 * q0) * 8;
  *(uint4*)(dst)       = make_uint4(pack2(w0.x, w0.y), pack2(w0.z, w0.w),
                                    pack2(w1.x, w1.y), pack2(w1.z, w1.w));
  *(uint4*)(dst + 128) = make_uint4(pack2(w2.x, w2.y), pack2(w2.z, w2.w),
                                    pack2(w3.x, w3.y), pack2(w3.z, w3.w));
}

// ---------------- fused GELU+dropout+GEMM: BM=64 x BN=512, 16 waves (4/SIMD) ----------------
// R13 configuration VERBATIM (best verified: fused 152.5 us, total 346.2).
// R14's 4-deep B ring spilled to scratch (WRITE +7 MB) and regressed — reverted.
// Mapping: same-stripe pair co-XCD; no-dup B (each frag loaded once/block); A-LDS XOR
// swizzle (conflict-free); 16 waves = 4/SIMD; 2-deep B reg dbuf; 1 barrier per 128-k chunk.
__global__ __launch_bounds__(1024, 4)
void fused_gemm_kernel(const float* __restrict__ X, const int* __restrict__ Mask,
                       const u16* __restrict__ Wt, const float* __restrict__ Bias,
                       float* __restrict__ Out) {
  __shared__ __attribute__((aligned(16))) u16 Abuf[2][8192];  // 2 x 16 KiB

  const int tid  = threadIdx.x;
  const int lane = tid & 63;
  const int wv   = tid >> 6;          // 0..15 : column sixteenth (32 cols)

  // ---- mapping (verified R11-R13): same-stripe pair co-XCD ----
  const int bid = blockIdx.x;
  const int xcd = bid & 7;
  const int j   = bid >> 3;                        // 0..31
  const int it  = xcd * 16 + (j >> 1);             // row tile 0..127
  const int jh  = j & 1;                           // column half 0/1
  const int m0  = it * 64;
  const int n0  = jh * 512;

  // ---- X/mask register staging: 8 elems/thread per 128-k chunk ----
  const int xrow = tid >> 4;          // 0..63
  const int xe8  = tid & 15;          // k-octet 0..15
  const float* Xp = X    + (size_t)(m0 + xrow) * K_DIM + xe8 * 8;
  const int*   Mp = Mask + (size_t)(m0 + xrow) * K_DIM + xe8 * 8;
  float4 xs0, xs1;
  uint4  ms0, ms1;
  auto loadX = [&](int c) {
    const float* xp = Xp + c * 128;
    const int*   mp = Mp + c * 128;
    xs0 = *(const float4*)(xp + 0);
    xs1 = *(const float4*)(xp + 4);
    ms0 = *(const uint4*)(mp + 0);
    ms1 = *(const uint4*)(mp + 4);
  };
  // A chunk layout (verified R12/R13): frag = kt*4+rf (1 KiB), slot (kq,r16) at kq*256+r16*16;
  // phys = logical ^ ((kt<<4)|((kq>>1)<<6)). Thread: kt=xe8>>2, kq=xe8&3 (one 16-B slot).
  const u32 kt_w = (u32)(xe8 >> 2), kq_w = (u32)(xe8 & 3);
  const u32 aBase = (((kt_w * 4 + (u32)(xrow >> 4)) * 1024) + kq_w * 256 +
                     (u32)(xrow & 15) * 16) ^
                    ((kt_w << 4) | ((kq_w >> 1) << 6));
  auto writeA = [&](int buf) {
    u32 o0 = pack2(gelu_drop(xs0.x, ms0.x), gelu_drop(xs0.y, ms0.y));
    u32 o1 = pack2(gelu_drop(xs0.z, ms0.z), gelu_drop(xs0.w, ms0.w));
    u32 o2 = pack2(gelu_drop(xs1.x, ms1.x), gelu_drop(xs1.y, ms1.y));
    u32 o3 = pack2(gelu_drop(xs1.z, ms1.z), gelu_drop(xs1.w, ms1.w));
    *(uint4*)((char*)Abuf[buf] + aBase) = make_uint4(o0, o1, o2, o3);
  };

  // ---- B: direct global->reg, 2 frags/wave/kt (wave cols = n0 + wv*32), dbuf 2 deep ----
  const char* WtB = (const char*)Wt;
  const size_t bBase = (size_t)(jh * 32 + wv * 2) * 131072 + (size_t)lane * 16;
  half8 bs0[2], bs1[2];
  auto loadB = [&](int kt, half8 (&bs)[2]) {
#pragma unroll
    for (int jj = 0; jj < 2; ++jj)
      bs[jj] = *(const half8*)(WtB + bBase + (size_t)jj * 131072 + (size_t)kt * 1024);
  };

  f32x4 acc[4][2];
#pragma unroll
  for (int i = 0; i < 4; ++i)
#pragma unroll
    for (int jj = 0; jj < 2; ++jj)
      acc[i][jj] = (f32x4){0.f, 0.f, 0.f, 0.f};

  // one kt step: 4 A ds_reads (swizzled, verified R12/R13) + 8 MFMA
  auto step = [&](int ab, int ktl, half8 (&bs)[2]) {
    const u32 rSwz = ((u32)ktl << 4) | (((u32)(lane >> 5) & 1u) << 6);
    half8 ar[4];
#pragma unroll
    for (int rf = 0; rf < 4; ++rf)
      ar[rf] = *(const half8*)((const char*)Abuf[ab] +
                               ((((u32)(ktl * 4 + rf) * 1024) + (u32)lane * 16) ^ rSwz));
    __builtin_amdgcn_s_setprio(1);
#pragma unroll
    for (int rf = 0; rf < 4; ++rf)
#pragma unroll
      for (int jj = 0; jj < 2; ++jj)
        acc[rf][jj] = __builtin_amdgcn_mfma_f32_16x16x32_f16(ar[rf], bs[jj], acc[rf][jj], 0, 0, 0);
    __builtin_amdgcn_s_setprio(0);
  };

  // ---- prologue ----
  loadX(0);
  writeA(0);          // chunk 0 -> buf 0 (compiler waits on X loads)
  loadX(1);           // for chunk 1 (written at c=0)
  loadB(0, bs0);
  loadB(1, bs1);
  asm volatile("s_waitcnt lgkmcnt(0)" ::: "memory");
  __builtin_amdgcn_s_barrier();

#pragma unroll 1
  for (int c = 0; c < 32; ++c) {
    const int ab = c & 1;
    const int kt0 = c * 4;
    // chunk-boundary A work: gelu chunk c+1 into other buf; issue X for chunk c+2
    if (c + 1 < 32) writeA(ab ^ 1);
    if (c + 2 < 32) loadX(c + 2);
    // 4 kt steps; B sets alternate, refilled right after consumption (depth 2)
    step(ab, 0, bs0);
    if (kt0 + 2 < 128) loadB(kt0 + 2, bs0);
    step(ab, 1, bs1);
    if (kt0 + 3 < 128) loadB(kt0 + 3, bs1);
    step(ab, 2, bs0);
    if (kt0 + 4 < 128) loadB(kt0 + 4, bs0);
    step(ab, 3, bs1);
    if (kt0 + 5 < 128) loadB(kt0 + 5, bs1);
    // barrier: next chunk reads buf ab^1 (written above by all threads)
    if (c + 1 < 32) {
      asm volatile("s_waitcnt lgkmcnt(0)" ::: "memory");
      __builtin_amdgcn_s_barrier();
    }
  }

  // ---- epilogue: C/D layout col = lane&15, row = (lane>>4)*4 + reg [verified R3-R13] ----
  const int fr = lane & 15;
  const int rq = (lane >> 4) << 2;
#pragma unroll
  for (int rf = 0; rf < 4; ++rf) {
    const int row0 = m0 + rf * 16 + rq;
#pragma unroll
    for (int jj = 0; jj < 2; ++jj) {
      const int col = n0 + wv * 32 + jj * 16 + fr;
      const float b = Bias[col];
#pragma unroll
      for (int r = 0; r < 4; ++r)
        Out[(size_t)(row0 + r) * N_DIM + col] = acc[rf][jj][r] + b;
    }
  }
}

// ---------------- fallback: verified R3 fused kernel (only if ws too small) ----------------
static constexpr int A_STRIDE = 40;

__global__ __launch_bounds__(256, 2)
void fused_fallback_kernel(const float* __restrict__ X, const float* __restrict__ W,
                           const float* __restrict__ Bias, const int* __restrict__ Mask,
                           float* __restrict__ Out) {
  __shared__ __attribute__((aligned(16))) _Float16 As[128 * A_STRIDE];
  __shared__ __attribute__((aligned(16))) _Float16 Bs[128 * 32];

  const int tid  = threadIdx.x;
  const int lane = tid & 63;
  const int wv   = tid >> 6;
  const int wr   = wv >> 1;
  const int wc   = wv & 1;
  const int bm = blockIdx.x & 63;
  const int bn = blockIdx.x >> 6;
  const int m0 = bm * 128;
  const int n0 = bn * 128;

  const int a_m = tid >> 1;
  const int a_k = (tid & 1) << 4;
  const float* xptr = X    + (size_t)(m0 + a_m) * K_DIM + a_k;
  const int*   mptr = Mask + (size_t)(m0 + a_m) * K_DIM + a_k;
  _Float16* a_lds = &As[a_m * A_STRIDE + a_k];

  const int i0 = tid, i1 = tid + 256;
  const float* wp0 = W + (size_t)(n0 + (i0 >> 2)) * K_DIM + ((i0 & 3) << 3);
  const float* wp1 = W + (size_t)(n0 + (i1 >> 2)) * K_DIM + ((i1 & 3) << 3);
  _Float16* bl0 = &Bs[i0 * 8];
  _Float16* bl1 = &Bs[i1 * 8];

  f32x4 acc[4][4];
#pragma unroll
  for (int i = 0; i < 4; ++i)
#pragma unroll
    for (int j = 0; j < 4; ++j)
      acc[i][j] = (f32x4){0.f, 0.f, 0.f, 0.f};

  float4 xf0 = *(const float4*)(xptr +  0);
  float4 xf1 = *(const float4*)(xptr +  4);
  float4 xf2 = *(const float4*)(xptr +  8);
  float4 xf3 = *(const float4*)(xptr + 12);
  uint4  mr0 = *(const uint4*)(mptr +  0);
  uint4  mr1 = *(const uint4*)(mptr +  4);
  uint4  mr2 = *(const uint4*)(mptr +  8);
  uint4  mr3 = *(const uint4*)(mptr + 12);
  float4 wf0 = *(const float4*)(wp0 + 0);
  float4 wf1 = *(const float4*)(wp0 + 4);
  float4 wf2 = *(const float4*)(wp1 + 0);
  float4 wf3 = *(const float4*)(wp1 + 4);

#pragma unroll 1
  for (int kt = 0; kt < 128; ++kt) {
    {
      float xs[16] = {xf0.x, xf0.y, xf0.z, xf0.w, xf1.x, xf1.y, xf1.z, xf1.w,
                      xf2.x, xf2.y, xf2.z, xf2.w, xf3.x, xf3.y, xf3.z, xf3.w};
      u32 mk[16]   = {mr0.x, mr0.y, mr0.z, mr0.w, mr1.x, mr1.y, mr1.z, mr1.w,
                      mr2.x, mr2.y, mr2.z, mr2.w, mr3.x, mr3.y, mr3.z, mr3.w};
      u32 ow[8];
#pragma unroll
      for (int e = 0; e < 8; ++e)
        ow[e] = pack2(gelu_drop(xs[2 * e], mk[2 * e]), gelu_drop(xs[2 * e + 1], mk[2 * e + 1]));
      ((uint4*)a_lds)[0] = make_uint4(ow[0], ow[1], ow[2], ow[3]);
      ((uint4*)a_lds)[1] = make_uint4(ow[4], ow[5], ow[6], ow[7]);
    }
    {
      *(uint4*)bl0 = make_uint4(pack2(wf0.x, wf0.y), pack2(wf0.z, wf0.w),
                                pack2(wf1.x, wf1.y), pack2(wf1.z, wf1.w));
      *(uint4*)bl1 = make_uint4(pack2(wf2.x, wf2.y), pack2(wf2.z, wf2.w),
                                pack2(wf3.x, wf3.y), pack2(wf3.z, wf3.w));
    }
    __syncthreads();

    if (kt + 1 < 128) {
      xptr += 32; mptr += 32; wp0 += 32; wp1 += 32;
      xf0 = *(const float4*)(xptr +  0);
      xf1 = *(const float4*)(xptr +  4);
      xf2 = *(const float4*)(xptr +  8);
      xf3 = *(const float4*)(xptr + 12);
      mr0 = *(const uint4*)(mptr +  0);
      mr1 = *(const uint4*)(mptr +  4);
      mr2 = *(const uint4*)(mptr +  8);
      mr3 = *(const uint4*)(mptr + 12);
      wf0 = *(const float4*)(wp0 + 0);
      wf1 = *(const float4*)(wp0 + 4);
      wf2 = *(const float4*)(wp1 + 0);
      wf3 = *(const float4*)(wp1 + 4);
    }

    {
      const int fr2 = lane & 15;
      const int fk2 = (lane >> 4) << 3;
      half8 ar[4], br[4];
#pragma unroll
      for (int i = 0; i < 4; ++i)
        ar[i] = *(const half8*)&As[(wr * 64 + i * 16 + fr2) * A_STRIDE + fk2];
#pragma unroll
      for (int j = 0; j < 4; ++j)
        br[j] = *(const half8*)&Bs[(wc * 64 + j * 16 + fr2) * 32 + fk2];
#pragma unroll
      for (int i = 0; i < 4; ++i)
#pragma unroll
        for (int j = 0; j < 4; ++j)
          acc[i][j] = __builtin_amdgcn_mfma_f32_16x16x32_f16(ar[i], br[j], acc[i][j], 0, 0, 0);
    }
    __syncthreads();
  }

  const int fr = lane & 15;
  const int rq = (lane >> 4) << 2;
  float bv[4];
#pragma unroll
  for (int j = 0; j < 4; ++j)
    bv[j] = Bias[n0 + wc * 64 + j * 16 + fr];
#pragma unroll
  for (int i = 0; i < 4; ++i) {
    const int row0 = m0 + wr * 64 + i * 16 + rq;
#pragma unroll
    for (int j = 0; j < 4; ++j) {
      const int col = n0 + wc * 64 + j * 16 + fr;
#pragma unroll
      for (int r = 0; r < 4; ++r)
        Out[(size_t)(row0 + r) * N_DIM + col] = acc[i][j][r] + bv[j];
    }
  }
}

extern "C" void kernel_launch(void* const* d_in, const int* in_sizes, int n_in,
                              void* d_out, int out_size, void* d_ws, size_t ws_size,
                              hipStream_t stream) {
  const float* X    = (const float*)d_in[0];   // x (8192x4096), fp16 canonicalized to f32
  const float* W    = (const float*)d_in[1];   // weight (1024x4096) f32, K-contiguous
  const float* Bias = (const float*)d_in[2];   // bias (1024) f32
  const int*   Mk   = (const int*)d_in[3];     // keep-mask int32 0/1
  float* Out = (float*)d_out;                  // y (8192x1024) f32

  if (ws_size >= WS_NEEDED) {
    u16* Wt = (u16*)d_ws;
    wpack_kernel<<<WPACK_BLOCKS, 256, 0, stream>>>(W, Wt);
    fused_gemm_kernel<<<256, 1024, 0, stream>>>(X, Mk, Wt, Bias, Out);
  } else {
    fused_fallback_kernel<<<64 * 8, 256, 0, stream>>>(X, W, Bias, Mk, Out);
  }
}